// Round 10
// baseline (504.662 us; speedup 1.0000x reference)
//
#include <hip/hip_runtime.h>
#include <hip/hip_bf16.h>

typedef __hip_bfloat16 bf16;
typedef __attribute__((ext_vector_type(8))) short short8;
typedef __attribute__((ext_vector_type(4))) float f32x4;

#define BB 8
#define QQ 900
#define DD 256
#define NH 8
#define HD 32
#define NPTS 4
#define FFD 1024
#define HH 100
#define WW2 100
#define HWTOT 10000

#define QT 64
#define KTC 128
#define NCHUNK ((QQ + KTC - 1) / KTC)  // 8
#define GQB 8                           // queries per gather block

__device__ inline float tofloat(float x) { return x; }
__device__ inline float tofloat(bf16 x) { return __bfloat162float(x); }
__device__ inline float bf2f(unsigned short u) {
    return __uint_as_float(((unsigned int)u) << 16);
}
__device__ inline void storev(bf16* p, float v) { *p = __float2bfloat16(v); }
__device__ inline void storev(float* p, float v) { *p = v; }
__device__ inline unsigned short f2bu(float v) {
    bf16 t = __float2bfloat16(v);
    return *(unsigned short*)&t;
}

// ---- 8-element register staging (load global -> regs now, regs -> LDS later) ----
template <typename T> struct Reg8;
template <> struct Reg8<float> {
    float4 a, b;
    __device__ void load(const float* p, size_t off, bool ok) {
        if (ok) {
            a = *(const float4*)(p + off);
            b = *(const float4*)(p + off + 4);
        } else {
            a = {0.f, 0.f, 0.f, 0.f};
            b = {0.f, 0.f, 0.f, 0.f};
        }
    }
    __device__ void store(unsigned short* dst) const {
        dst[0] = f2bu(a.x); dst[1] = f2bu(a.y); dst[2] = f2bu(a.z); dst[3] = f2bu(a.w);
        dst[4] = f2bu(b.x); dst[5] = f2bu(b.y); dst[6] = f2bu(b.z); dst[7] = f2bu(b.w);
    }
};
template <> struct Reg8<bf16> {
    uint4 u;
    __device__ void load(const bf16* p, size_t off, bool ok) {
        const uint4 z = {0u, 0u, 0u, 0u};
        u = ok ? *(const uint4*)((const unsigned short*)p + off) : z;
    }
    __device__ void store(unsigned short* dst) const { *(uint4*)dst = u; }
};

// ---------------- pack kernel: fp32 weights -> bf16 workspace ----------
__global__ void pack_kernel(const float* __restrict__ in_proj_w, const float* __restrict__ out_proj_w,
                            const float* __restrict__ cout_w, const float* __restrict__ ffn_w1,
                            const float* __restrict__ ffn_w2, const float* __restrict__ vproj_w,
                            const float* __restrict__ offs_w, const float* __restrict__ attw_w,
                            const float* __restrict__ ref_w, const float* __restrict__ offs_b,
                            const float* __restrict__ attw_b, const float* __restrict__ ref_b,
                            bf16* __restrict__ wpk, float* __restrict__ dbias) {
    const int idx = blockIdx.x * 256 + threadIdx.x;
    const int TOT = 950272 + 128;
    if (idx >= TOT) return;
    if (idx < 196608) {
        wpk[idx] = __float2bfloat16(in_proj_w[idx]);
    } else if (idx < 262144) {
        wpk[idx] = __float2bfloat16(out_proj_w[idx - 196608]);
    } else if (idx < 327680) {
        wpk[idx] = __float2bfloat16(cout_w[idx - 262144]);
    } else if (idx < 589824) {
        wpk[idx] = __float2bfloat16(ffn_w1[idx - 327680]);
    } else if (idx < 851968) {
        wpk[idx] = __float2bfloat16(ffn_w2[idx - 589824]);
    } else if (idx < 917504) {
        wpk[idx] = __float2bfloat16(vproj_w[idx - 851968]);
    } else if (idx < 950272) {
        const int j = idx - 917504;
        const int r = j >> 8, c = j & 255;
        float v = 0.f;
        if (r < 64) v = offs_w[r * 256 + c];
        else if (r < 96) v = attw_w[(r - 64) * 256 + c];
        else if (r < 98) v = ref_w[(r - 96) * 256 + c];
        wpk[idx] = __float2bfloat16(v);
    } else {
        const int j = idx - 950272;
        float v = 0.f;
        if (j < 64) v = offs_b[j];
        else if (j < 96) v = attw_b[j - 64];
        else if (j < 98) v = ref_b[j - 96];
        dbias[j] = v;
    }
}

// ---- 64-element row-segment load/store helpers (16B vectorized) ----
__device__ inline void load64(float* v, const float* p) {
#pragma unroll
    for (int j = 0; j < 16; ++j) {
        const float4 q = ((const float4*)p)[j];
        v[j * 4] = q.x; v[j * 4 + 1] = q.y; v[j * 4 + 2] = q.z; v[j * 4 + 3] = q.w;
    }
}
__device__ inline void load64(float* v, const bf16* p) {
#pragma unroll
    for (int j = 0; j < 8; ++j) {
        const uint4 u = ((const uint4*)p)[j];
        const unsigned short* s = (const unsigned short*)&u;
#pragma unroll
        for (int i = 0; i < 8; ++i) v[j * 8 + i] = bf2f(s[i]);
    }
}
__device__ inline void store64(bf16* p, const float* w) {
#pragma unroll
    for (int j = 0; j < 8; ++j) {
        unsigned short t[8];
#pragma unroll
        for (int i = 0; i < 8; ++i) t[i] = f2bu(w[j * 8 + i]);
        ((uint4*)p)[j] = *(uint4*)t;
    }
}
__device__ inline void store64(float* p, const float* w) {
#pragma unroll
    for (int j = 0; j < 16; ++j) {
        float4 q = {w[j * 4], w[j * 4 + 1], w[j * 4 + 2], w[j * 4 + 3]};
        ((float4*)p)[j] = q;
    }
}

// ---------------- WIDE MFMA GEMM: BM=64, BN=256, register-prefetch pipeline ----------
// C = A[M,K] @ W[N,K]^T + bias; EPI: 0=none, 1=relu, 2=LayerNorm(resid + C).
// EPI=2 requires N==256, gridDim.x==1.
template <int EPI, typename TA, typename TR, typename OT>
__global__ __launch_bounds__(256) void wide_gemm_kernel(
    const TA* __restrict__ A, const bf16* __restrict__ W, const float* __restrict__ bias,
    const TR* __restrict__ resid, const float* __restrict__ gamma, const float* __restrict__ beta,
    OT* __restrict__ C, int M, int N, int K) {
    __shared__ unsigned short smem[16896];  // 33792 B
    unsigned short (*As)[40] = (unsigned short(*)[40])smem;            // 64 x 40
    unsigned short (*Bs)[40] = (unsigned short(*)[40])(smem + 2560);   // 256 x 40
    unsigned short (*Cst)[264] = (unsigned short(*)[264])smem;         // 64 x 264 (overlay)
    const int bm = blockIdx.y * 64, bn = blockIdx.x * 256;
    const int tid = threadIdx.x;
    const int lane = tid & 63, wave = tid >> 6;
    const int l15 = lane & 15, g = lane >> 4;
    const f32x4 zf = {0.f, 0.f, 0.f, 0.f};
    f32x4 acc[16];
#pragma unroll
    for (int ct = 0; ct < 16; ++ct) acc[ct] = zf;

    const int sr = tid >> 2, sc = (tid & 3) * 8;
    const bool aok = (bm + sr) < M;
    bool bok[4];
#pragma unroll
    for (int p = 0; p < 4; ++p) bok[p] = (bn + sr + p * 64) < N;

    Reg8<TA> ra;
    Reg8<bf16> rb[4];
    ra.load(A, (size_t)(bm + sr) * K + sc, aok);
#pragma unroll
    for (int p = 0; p < 4; ++p) rb[p].load(W, (size_t)(bn + sr + p * 64) * K + sc, bok[p]);

    for (int k0 = 0; k0 < K; k0 += 32) {
        __syncthreads();
        ra.store(&As[sr][sc]);
#pragma unroll
        for (int p = 0; p < 4; ++p) rb[p].store(&Bs[sr + p * 64][sc]);
        __syncthreads();
        if (k0 + 32 < K) {  // issue next-step loads; they overlap the MFMAs below
            ra.load(A, (size_t)(bm + sr) * K + k0 + 32 + sc, aok);
#pragma unroll
            for (int p = 0; p < 4; ++p)
                rb[p].load(W, (size_t)(bn + sr + p * 64) * K + k0 + 32 + sc, bok[p]);
        }
        const short8 af = *(const short8*)&As[wave * 16 + l15][g * 8];
#pragma unroll
        for (int ct = 0; ct < 16; ++ct) {
            const short8 bf = *(const short8*)&Bs[ct * 16 + l15][g * 8];
            acc[ct] = __builtin_amdgcn_mfma_f32_16x16x32_bf16(af, bf, acc[ct], 0, 0, 0);
        }
    }
    // ---- stage C (bias/relu applied, bf16) ----
    __syncthreads();
#pragma unroll
    for (int ct = 0; ct < 16; ++ct) {
        const int col = ct * 16 + l15;
        const float bv = bias[bn + col];
#pragma unroll
        for (int r = 0; r < 4; ++r) {
            float v = acc[ct][r] + bv;
            if (EPI == 1) v = fmaxf(v, 0.f);
            Cst[wave * 16 + g * 4 + r][col] = f2bu(v);
        }
    }
    __syncthreads();
    // ---- write phase: 4 threads per row, 64 cols each ----
    const int r = tid >> 2, sub = tid & 3;
    const int row = bm + r;
    if (row >= M) return;
    if (EPI < 2) {
        uint4* dst = (uint4*)((unsigned short*)C + (size_t)row * N + bn + sub * 64);
#pragma unroll
        for (int j = 0; j < 8; ++j) dst[j] = *(const uint4*)&Cst[r][sub * 64 + j * 8];
    } else {
        float v[64];
        load64(v, resid + (size_t)row * 256 + sub * 64);
        float s = 0.f;
#pragma unroll
        for (int j = 0; j < 8; ++j) {
            const uint4 u = *(const uint4*)&Cst[r][sub * 64 + j * 8];
            const unsigned short* us = (const unsigned short*)&u;
#pragma unroll
            for (int i = 0; i < 8; ++i) {
                v[j * 8 + i] += bf2f(us[i]);
                s += v[j * 8 + i];
            }
        }
        s += __shfl_xor(s, 1);
        s += __shfl_xor(s, 2);
        const float mean = s * (1.f / 256.f);
        float s2 = 0.f;
#pragma unroll
        for (int i = 0; i < 64; ++i) {
            const float d = v[i] - mean;
            s2 += d * d;
        }
        s2 += __shfl_xor(s2, 1);
        s2 += __shfl_xor(s2, 2);
        const float rstd = rsqrtf(s2 * (1.f / 256.f) + 1e-5f);
#pragma unroll
        for (int i = 0; i < 64; ++i) {
            const int c = sub * 64 + i;
            v[i] = (v[i] - mean) * rstd * gamma[c] + beta[c];
        }
        store64(C + (size_t)row * 256 + sub * 64, v);
    }
}

// ---------------- narrow MFMA GEMM (dots): BM=128, BN=64, prefetch ----------------
template <int ACT, typename TA, typename OT>
__global__ __launch_bounds__(256) void gemm_mfma_kernel(const TA* __restrict__ A,
                                                        const bf16* __restrict__ W,
                                                        const float* __restrict__ bias,
                                                        OT* __restrict__ C, int M, int N, int K) {
    __shared__ unsigned short As[128][40];
    __shared__ unsigned short Bs[64][40];
    const int bm = blockIdx.y * 128, bn = blockIdx.x * 64;
    const int tid = threadIdx.x;
    const int lane = tid & 63, wave = tid >> 6;
    const int l15 = lane & 15, g = lane >> 4;
    const f32x4 zf = {0.f, 0.f, 0.f, 0.f};
    f32x4 acc[2][4];
#pragma unroll
    for (int rt = 0; rt < 2; ++rt)
#pragma unroll
        for (int ct = 0; ct < 4; ++ct) acc[rt][ct] = zf;

    const int ar0 = tid >> 2, ac0 = (tid & 3) * 8;       // pass 0
    const int ar1 = (tid + 256) >> 2, ac1 = ac0;         // pass 1
    const bool aok0 = (bm + ar0) < M, aok1 = (bm + ar1) < M;
    const bool bokk = (bn + ar0) < N;

    Reg8<TA> ra[2];
    Reg8<bf16> rb;
    ra[0].load(A, (size_t)(bm + ar0) * K + ac0, aok0);
    ra[1].load(A, (size_t)(bm + ar1) * K + ac1, aok1);
    rb.load(W, (size_t)(bn + ar0) * K + ac0, bokk);

    for (int k0 = 0; k0 < K; k0 += 32) {
        __syncthreads();
        ra[0].store(&As[ar0][ac0]);
        ra[1].store(&As[ar1][ac1]);
        rb.store(&Bs[ar0][ac0]);
        __syncthreads();
        if (k0 + 32 < K) {
            ra[0].load(A, (size_t)(bm + ar0) * K + k0 + 32 + ac0, aok0);
            ra[1].load(A, (size_t)(bm + ar1) * K + k0 + 32 + ac1, aok1);
            rb.load(W, (size_t)(bn + ar0) * K + k0 + 32 + ac0, bokk);
        }
        short8 af[2];
        af[0] = *(const short8*)&As[wave * 32 + l15][g * 8];
        af[1] = *(const short8*)&As[wave * 32 + 16 + l15][g * 8];
#pragma unroll
        for (int ct = 0; ct < 4; ++ct) {
            const short8 bf = *(const short8*)&Bs[ct * 16 + l15][g * 8];
            acc[0][ct] = __builtin_amdgcn_mfma_f32_16x16x32_bf16(af[0], bf, acc[0][ct], 0, 0, 0);
            acc[1][ct] = __builtin_amdgcn_mfma_f32_16x16x32_bf16(af[1], bf, acc[1][ct], 0, 0, 0);
        }
    }
#pragma unroll
    for (int rt = 0; rt < 2; ++rt)
#pragma unroll
        for (int ct = 0; ct < 4; ++ct) {
            const int col = bn + ct * 16 + l15;
            const float bv = bias[col];
#pragma unroll
            for (int r = 0; r < 4; ++r) {
                const int row = bm + wave * 32 + rt * 16 + g * 4 + r;
                if (row < M) {
                    float v = acc[rt][ct][r] + bv;
                    if (ACT == 1) v = fmaxf(v, 0.f);
                    storev(&C[(size_t)row * N + col], v);
                }
            }
        }
}

// ---------------- MFMA flash MHA with K/V register prefetch ----------------
__global__ __launch_bounds__(256) void mha_mfma_kernel(const bf16* __restrict__ qkv,
                                                       bf16* __restrict__ o) {
    const int qt = blockIdx.x, h = blockIdx.y, b = blockIdx.z;
    const int tid = threadIdx.x;
    const int lane = tid & 63, wave = tid >> 6;
    const int l15 = lane & 15, g = lane >> 4;
    __shared__ unsigned short Kls[KTC][40];
    __shared__ bf16 Vt[HD][136];
    __shared__ bf16 Pls[4][16][136];
    const size_t base = (size_t)b * QQ * 768;
    const int q0 = qt * QT;

    short8 qa = {0, 0, 0, 0, 0, 0, 0, 0};
    {
        const int qg = q0 + wave * 16 + l15;
        if (qg < QQ)
            qa = *(const short8*)(qkv + base + (size_t)qg * 768 + h * HD + g * 8);
    }
    f32x4 accO[2] = {{0.f, 0.f, 0.f, 0.f}, {0.f, 0.f, 0.f, 0.f}};
    float m_run[4], l_run[4];
#pragma unroll
    for (int r = 0; r < 4; ++r) {
        m_run[r] = -1e30f;
        l_run[r] = 0.f;
    }
    const float scale = 0.17677669529663687f;
    const uint4 zero4 = {0u, 0u, 0u, 0u};

    const int kpart = tid & 3, kr = tid >> 2;          // K staging map
    const int vr = tid >> 1, vch = (tid & 1) * 16;     // V staging map
    uint4 kreg[2], vreg[2];
    // prologue: load chunk 0
    {
#pragma unroll
        for (int pass = 0; pass < 2; ++pass) {
            const int kg = kr + pass * 64;
            kreg[pass] = (kg < QQ)
                ? *(const uint4*)(qkv + base + (size_t)kg * 768 + DD + h * HD + kpart * 8)
                : zero4;
        }
        if (vr < QQ) {
            const bf16* pv = qkv + base + (size_t)vr * 768 + 2 * DD + h * HD + vch;
            vreg[0] = *(const uint4*)pv;
            vreg[1] = *(const uint4*)(pv + 8);
        } else {
            vreg[0] = zero4;
            vreg[1] = zero4;
        }
    }

    for (int c = 0; c < NCHUNK; ++c) {
        const int k0 = c * KTC;
        __syncthreads();
#pragma unroll
        for (int pass = 0; pass < 2; ++pass) *(uint4*)&Kls[kr + pass * 64][kpart * 8] = kreg[pass];
        {
            const unsigned short* u0 = (const unsigned short*)&vreg[0];
            const unsigned short* u1 = (const unsigned short*)&vreg[1];
#pragma unroll
            for (int j = 0; j < 8; ++j) {
                ((unsigned short*)&Vt[vch + j][vr])[0] = u0[j];
                ((unsigned short*)&Vt[vch + 8 + j][vr])[0] = u1[j];
            }
        }
        __syncthreads();
        if (c + 1 < NCHUNK) {  // prefetch next chunk
            const int kn = k0 + KTC;
#pragma unroll
            for (int pass = 0; pass < 2; ++pass) {
                const int kg = kn + kr + pass * 64;
                kreg[pass] = (kg < QQ)
                    ? *(const uint4*)(qkv + base + (size_t)kg * 768 + DD + h * HD + kpart * 8)
                    : zero4;
            }
            const int vg = kn + vr;
            if (vg < QQ) {
                const bf16* pv = qkv + base + (size_t)vg * 768 + 2 * DD + h * HD + vch;
                vreg[0] = *(const uint4*)pv;
                vreg[1] = *(const uint4*)(pv + 8);
            } else {
                vreg[0] = zero4;
                vreg[1] = zero4;
            }
        }

        f32x4 s[8];
#pragma unroll
        for (int t = 0; t < 8; ++t) {
            const short8 kb = *(const short8*)&Kls[t * 16 + l15][g * 8];
            const f32x4 z = {0.f, 0.f, 0.f, 0.f};
            s[t] = __builtin_amdgcn_mfma_f32_16x16x32_bf16(qa, kb, z, 0, 0, 0);
        }
        float mx[4] = {-1e30f, -1e30f, -1e30f, -1e30f};
#pragma unroll
        for (int t = 0; t < 8; ++t) {
            const bool cv = (k0 + t * 16 + l15) < QQ;
#pragma unroll
            for (int r = 0; r < 4; ++r) {
                const float v = cv ? s[t][r] * scale : -1e30f;
                s[t][r] = v;
                mx[r] = fmaxf(mx[r], v);
            }
        }
#pragma unroll
        for (int r = 0; r < 4; ++r) {
            mx[r] = fmaxf(mx[r], __shfl_xor(mx[r], 1));
            mx[r] = fmaxf(mx[r], __shfl_xor(mx[r], 2));
            mx[r] = fmaxf(mx[r], __shfl_xor(mx[r], 4));
            mx[r] = fmaxf(mx[r], __shfl_xor(mx[r], 8));
        }
        float alpha[4], rs[4];
#pragma unroll
        for (int r = 0; r < 4; ++r) {
            const float mn = fmaxf(m_run[r], mx[r]);
            alpha[r] = __expf(m_run[r] - mn);
            m_run[r] = mn;
            rs[r] = 0.f;
        }
#pragma unroll
        for (int t = 0; t < 8; ++t) {
#pragma unroll
            for (int r = 0; r < 4; ++r) {
                const float p = __expf(s[t][r] - m_run[r]);
                rs[r] += p;
                Pls[wave][g * 4 + r][t * 16 + l15] = __float2bfloat16(p);
            }
        }
#pragma unroll
        for (int r = 0; r < 4; ++r) {
            rs[r] += __shfl_xor(rs[r], 1);
            rs[r] += __shfl_xor(rs[r], 2);
            rs[r] += __shfl_xor(rs[r], 4);
            rs[r] += __shfl_xor(rs[r], 8);
            l_run[r] = l_run[r] * alpha[r] + rs[r];
        }
#pragma unroll
        for (int t2 = 0; t2 < 2; ++t2)
#pragma unroll
            for (int r = 0; r < 4; ++r) accO[t2][r] *= alpha[r];
#pragma unroll
        for (int s4 = 0; s4 < 4; ++s4) {
            const short8 pa = *(const short8*)&Pls[wave][l15][s4 * 32 + g * 8];
#pragma unroll
            for (int t2 = 0; t2 < 2; ++t2) {
                const short8 vb = *(const short8*)&Vt[t2 * 16 + l15][s4 * 32 + g * 8];
                accO[t2] = __builtin_amdgcn_mfma_f32_16x16x32_bf16(pa, vb, accO[t2], 0, 0, 0);
            }
        }
    }
#pragma unroll
    for (int r = 0; r < 4; ++r) {
        const int row = q0 + wave * 16 + g * 4 + r;
        if (row < QQ) {
            const float inv = 1.f / l_run[r];
#pragma unroll
            for (int t2 = 0; t2 < 2; ++t2) {
                storev(&o[((size_t)b * QQ + row) * DD + h * HD + t2 * 16 + l15],
                       accO[t2][r] * inv);
            }
        }
    }
}

// ---------------- deformable gather from precomputed val ----------------
__global__ __launch_bounds__(256) void deform_gather_kernel(const float* __restrict__ dots,
                                                            const bf16* __restrict__ val,
                                                            bf16* __restrict__ samp) {
    const int b = blockIdx.y;
    const int q0 = blockIdx.x * GQB;
    const int tid = threadIdx.x;
    const int q = tid >> 5, hp = tid & 31, h = hp >> 2;
    const int qg = q0 + q;
    __shared__ float Gs[GQB][32][36];
    float accv[32];
#pragma unroll
    for (int j = 0; j < 32; ++j) accv[j] = 0.f;

    if (qg < QQ) {
        const float* dr = dots + ((size_t)b * QQ + qg) * 128;
        const float ox = dr[hp * 2], oy = dr[hp * 2 + 1];
        const float ad = dr[64 + hp];
        const float rx = dr[96], ry = dr[97];
        float mx = ad;
        mx = fmaxf(mx, __shfl_xor(mx, 1));
        mx = fmaxf(mx, __shfl_xor(mx, 2));
        const float e = __expf(ad - mx);
        float sm = e;
        sm += __shfl_xor(sm, 1);
        sm += __shfl_xor(sm, 2);
        const float a = e / sm;
        const float refx = 1.f / (1.f + __expf(-rx));
        const float refy = 1.f / (1.f + __expf(-ry));
        const float x = (refx + ox * (1.f / WW2)) * WW2 - 0.5f;
        const float y = (refy + oy * (1.f / HH)) * HH - 0.5f;
        const float x0f = floorf(x), y0f = floorf(y);
        const float lx = x - x0f, ly = y - y0f;
        const int x0 = (int)x0f, y0 = (int)y0f;
        const float cw[4] = {(1 - lx) * (1 - ly), lx * (1 - ly), (1 - lx) * ly, lx * ly};
        const int cx[4] = {x0, x0 + 1, x0, x0 + 1};
        const int cy[4] = {y0, y0, y0 + 1, y0 + 1};
        const bf16* vb = val + (size_t)b * HWTOT * DD + h * HD;
#pragma unroll
        for (int cc = 0; cc < 4; ++cc) {
            const bool valid = cx[cc] >= 0 && cx[cc] < WW2 && cy[cc] >= 0 && cy[cc] < HH;
            const float w = valid ? a * cw[cc] : 0.f;
            const int xi = min(max(cx[cc], 0), WW2 - 1);
            const int yi = min(max(cy[cc], 0), HH - 1);
            const bf16* p = vb + (size_t)(yi * WW2 + xi) * DD;
            const uint4 u0 = *(const uint4*)p;
            const uint4 u1 = *(const uint4*)(p + 8);
            const uint4 u2 = *(const uint4*)(p + 16);
            const uint4 u3 = *(const uint4*)(p + 24);
            const unsigned short* s0 = (const unsigned short*)&u0;
            const unsigned short* s1 = (const unsigned short*)&u1;
            const unsigned short* s2 = (const unsigned short*)&u2;
            const unsigned short* s3 = (const unsigned short*)&u3;
#pragma unroll
            for (int j = 0; j < 8; ++j) {
                accv[j] += w * bf2f(s0[j]);
                accv[8 + j] += w * bf2f(s1[j]);
                accv[16 + j] += w * bf2f(s2[j]);
                accv[24 + j] += w * bf2f(s3[j]);
            }
        }
    }
#pragma unroll
    for (int j4 = 0; j4 < 8; ++j4) {
        float4 t = {accv[j4 * 4], accv[j4 * 4 + 1], accv[j4 * 4 + 2], accv[j4 * 4 + 3]};
        *(float4*)&Gs[q][hp][j4 * 4] = t;
    }
    __syncthreads();
    {
        const int q2 = tid >> 5, idx5 = tid & 31;
        const int h2 = idx5 >> 2, cg = idx5 & 3;
        if (q0 + q2 < QQ) {
            float s[8] = {0.f, 0.f, 0.f, 0.f, 0.f, 0.f, 0.f, 0.f};
#pragma unroll
            for (int p = 0; p < 4; ++p) {
                const float4 a0 = *(const float4*)&Gs[q2][h2 * 4 + p][cg * 8];
                const float4 a1 = *(const float4*)&Gs[q2][h2 * 4 + p][cg * 8 + 4];
                s[0] += a0.x; s[1] += a0.y; s[2] += a0.z; s[3] += a0.w;
                s[4] += a1.x; s[5] += a1.y; s[6] += a1.z; s[7] += a1.w;
            }
            unsigned short outp[8];
#pragma unroll
            for (int j = 0; j < 8; ++j) outp[j] = f2bu(s[j]);
            bf16* op = samp + ((size_t)b * QQ + q0 + q2) * DD + h2 * HD + cg * 8;
            *(uint4*)op = *(uint4*)outp;
        }
    }
}

extern "C" void kernel_launch(void* const* d_in, const int* in_sizes, int n_in,
                              void* d_out, int out_size, void* d_ws, size_t ws_size,
                              hipStream_t stream) {
    const float* tgt = (const float*)d_in[0];
    const float* memory = (const float*)d_in[1];
    const float* in_proj_w = (const float*)d_in[4];
    const float* in_proj_b = (const float*)d_in[5];
    const float* out_proj_w = (const float*)d_in[6];
    const float* out_proj_b = (const float*)d_in[7];
    const float* norm1_s = (const float*)d_in[8];
    const float* norm1_b = (const float*)d_in[9];
    const float* norm2_s = (const float*)d_in[10];
    const float* norm2_b = (const float*)d_in[11];
    const float* norm3_s = (const float*)d_in[12];
    const float* norm3_b = (const float*)d_in[13];
    const float* vproj_w = (const float*)d_in[14];
    const float* vproj_b = (const float*)d_in[15];
    const float* offs_w = (const float*)d_in[16];
    const float* offs_b = (const float*)d_in[17];
    const float* attw_w = (const float*)d_in[18];
    const float* attw_b = (const float*)d_in[19];
    const float* ref_w = (const float*)d_in[20];
    const float* ref_b = (const float*)d_in[21];
    const float* cout_w = (const float*)d_in[22];
    const float* cout_b = (const float*)d_in[23];
    const float* ffn_w1 = (const float*)d_in[24];
    const float* ffn_b1 = (const float*)d_in[25];
    const float* ffn_w2 = (const float*)d_in[26];
    const float* ffn_b2 = (const float*)d_in[27];

    const int M = BB * QQ;  // 7200
    bf16* ws = (bf16*)d_ws;
    size_t off = 0;
    bf16* qkv = ws + off;  off += (size_t)M * 768;
    bf16* o = ws + off;    off += (size_t)M * DD;
    bf16* t1 = ws + off;   off += (size_t)M * DD;
    bf16* ffh = ws + off;  off += (size_t)M * FFD;
    bf16* wpk = ws + off;  off += 950272;
    float* dbias = (float*)(ws + off); off += 256;
    bf16* val = ws + off;  off += (size_t)BB * HWTOT * DD;
    bf16* samp = o;                     // alias: o dead after out_proj
    bf16* t2n = qkv;                    // alias: qkv dead after mha
    float* dots = (float*)ffh;          // alias: ffh written only after gather

    bf16* w_in = wpk;
    bf16* w_out = wpk + 196608;
    bf16* w_cout = wpk + 262144;
    bf16* w_ffn1 = wpk + 327680;
    bf16* w_ffn2 = wpk + 589824;
    bf16* w_vproj = wpk + 851968;
    bf16* w_dots = wpk + 917504;

    const int MT64 = (M + 63) / 64;  // 113

    // 0. pack weights to bf16
    pack_kernel<<<(950272 + 128 + 255) / 256, 256, 0, stream>>>(
        in_proj_w, out_proj_w, cout_w, ffn_w1, ffn_w2, vproj_w, offs_w, attw_w, ref_w,
        offs_b, attw_b, ref_b, wpk, dbias);
    // 1. value projection (wide, A read once, prefetch-pipelined)
    wide_gemm_kernel<0, float, float, bf16><<<dim3(1, BB * HWTOT / 64), 256, 0, stream>>>(
        memory, w_vproj, vproj_b, nullptr, nullptr, nullptr, val, BB * HWTOT, DD, DD);
    // 2. QKV projection
    wide_gemm_kernel<0, float, float, bf16><<<dim3(3, MT64), 256, 0, stream>>>(
        tgt, w_in, in_proj_b, nullptr, nullptr, nullptr, qkv, M, 768, DD);
    // 3. self-attention
    mha_mfma_kernel<<<dim3((QQ + QT - 1) / QT, NH, BB), 256, 0, stream>>>(qkv, o);
    // 4. out projection + LN1 fused (resid = tgt fp32) -> t1 bf16
    wide_gemm_kernel<2, bf16, float, bf16><<<dim3(1, MT64), 256, 0, stream>>>(
        o, w_out, out_proj_b, tgt, norm1_s, norm1_b, t1, M, DD, DD);
    // 5. deform param dots GEMM -> fp32 [M,128]
    gemm_mfma_kernel<0, bf16, float><<<dim3(2, (M + 127) / 128), 256, 0, stream>>>(
        t1, w_dots, dbias, dots, M, 128, DD);
    // 6. gather from val
    deform_gather_kernel<<<dim3((QQ + GQB - 1) / GQB, BB), 256, 0, stream>>>(dots, val, samp);
    // 7. cross-attn out projection + LN2 fused (resid = t1) -> t2n bf16
    wide_gemm_kernel<2, bf16, bf16, bf16><<<dim3(1, MT64), 256, 0, stream>>>(
        samp, w_cout, cout_b, t1, norm2_s, norm2_b, t2n, M, DD, DD);
    // 8. FFN layer 1 (+ReLU)
    wide_gemm_kernel<1, bf16, float, bf16><<<dim3(4, MT64), 256, 0, stream>>>(
        t2n, w_ffn1, ffn_b1, nullptr, nullptr, nullptr, ffh, M, FFD, DD);
    // 9. FFN layer 2 + LN3 fused (resid = t2n) -> fp32 d_out
    wide_gemm_kernel<2, bf16, bf16, float><<<dim3(1, MT64), 256, 0, stream>>>(
        ffh, w_ffn2, ffn_b2, t2n, norm3_s, norm3_b, (float*)d_out, M, DD, FFD);
}

// Round 11
// 422.576 us; speedup vs baseline: 1.1943x; 1.1943x over previous
//
#include <hip/hip_runtime.h>
#include <hip/hip_bf16.h>

typedef __hip_bfloat16 bf16;
typedef __attribute__((ext_vector_type(8))) short short8;
typedef __attribute__((ext_vector_type(4))) float f32x4;

#define BB 8
#define QQ 900
#define DD 256
#define NH 8
#define HD 32
#define NPTS 4
#define FFD 1024
#define HH 100
#define WW2 100
#define HWTOT 10000

#define QT 64
#define KTC 128
#define NCHUNK ((QQ + KTC - 1) / KTC)  // 8
#define GQB 8                           // queries per gather block

__device__ inline float tofloat(float x) { return x; }
__device__ inline float tofloat(bf16 x) { return __bfloat162float(x); }
__device__ inline float bf2f(unsigned short u) {
    return __uint_as_float(((unsigned int)u) << 16);
}
__device__ inline void storev(bf16* p, float v) { *p = __float2bfloat16(v); }
__device__ inline void storev(float* p, float v) { *p = v; }
__device__ inline unsigned short f2bu(float v) {
    bf16 t = __float2bfloat16(v);
    return *(unsigned short*)&t;
}

// ---------------- pack kernel: fp32 weights -> bf16 workspace ----------
__global__ void pack_kernel(const float* __restrict__ in_proj_w, const float* __restrict__ out_proj_w,
                            const float* __restrict__ cout_w, const float* __restrict__ ffn_w1,
                            const float* __restrict__ ffn_w2, const float* __restrict__ vproj_w,
                            const float* __restrict__ offs_w, const float* __restrict__ attw_w,
                            const float* __restrict__ ref_w, const float* __restrict__ offs_b,
                            const float* __restrict__ attw_b, const float* __restrict__ ref_b,
                            bf16* __restrict__ wpk, float* __restrict__ dbias) {
    const int idx = blockIdx.x * 256 + threadIdx.x;
    const int TOT = 950272 + 128;
    if (idx >= TOT) return;
    if (idx < 196608) {
        wpk[idx] = __float2bfloat16(in_proj_w[idx]);
    } else if (idx < 262144) {
        wpk[idx] = __float2bfloat16(out_proj_w[idx - 196608]);
    } else if (idx < 327680) {
        wpk[idx] = __float2bfloat16(cout_w[idx - 262144]);
    } else if (idx < 589824) {
        wpk[idx] = __float2bfloat16(ffn_w1[idx - 327680]);
    } else if (idx < 851968) {
        wpk[idx] = __float2bfloat16(ffn_w2[idx - 589824]);
    } else if (idx < 917504) {
        wpk[idx] = __float2bfloat16(vproj_w[idx - 851968]);
    } else if (idx < 950272) {
        const int j = idx - 917504;
        const int r = j >> 8, c = j & 255;
        float v = 0.f;
        if (r < 64) v = offs_w[r * 256 + c];
        else if (r < 96) v = attw_w[(r - 64) * 256 + c];
        else if (r < 98) v = ref_w[(r - 96) * 256 + c];
        wpk[idx] = __float2bfloat16(v);
    } else {
        const int j = idx - 950272;
        float v = 0.f;
        if (j < 64) v = offs_b[j];
        else if (j < 96) v = attw_b[j - 64];
        else if (j < 98) v = ref_b[j - 96];
        dbias[j] = v;
    }
}

// ---- staging helpers: 8 contiguous elements -> 8 bf16 in LDS ----
__device__ inline void stage8(unsigned short* dst, const bf16* A, size_t off, bool ok) {
    const uint4 z = {0u, 0u, 0u, 0u};
    *(uint4*)dst = ok ? *(const uint4*)((const unsigned short*)A + off) : z;
}
__device__ inline void stage8(unsigned short* dst, const float* A, size_t off, bool ok) {
    if (ok) {
        const float4 f0 = *(const float4*)(A + off);
        const float4 f1 = *(const float4*)(A + off + 4);
        dst[0] = f2bu(f0.x); dst[1] = f2bu(f0.y); dst[2] = f2bu(f0.z); dst[3] = f2bu(f0.w);
        dst[4] = f2bu(f1.x); dst[5] = f2bu(f1.y); dst[6] = f2bu(f1.z); dst[7] = f2bu(f1.w);
    } else {
        const uint4 z = {0u, 0u, 0u, 0u};
        *(uint4*)dst = z;
    }
}

// ---- 32-element row-segment load/store helpers (16B vectorized) ----
__device__ inline void load32(float* v, const float* p) {
#pragma unroll
    for (int j = 0; j < 8; ++j) {
        const float4 q = ((const float4*)p)[j];
        v[j * 4] = q.x; v[j * 4 + 1] = q.y; v[j * 4 + 2] = q.z; v[j * 4 + 3] = q.w;
    }
}
__device__ inline void load32(float* v, const bf16* p) {
#pragma unroll
    for (int j = 0; j < 4; ++j) {
        const uint4 u = ((const uint4*)p)[j];
        const unsigned short* s = (const unsigned short*)&u;
#pragma unroll
        for (int i = 0; i < 8; ++i) v[j * 8 + i] = bf2f(s[i]);
    }
}
__device__ inline void store32(bf16* p, const float* w) {
#pragma unroll
    for (int j = 0; j < 4; ++j) {
        unsigned short t[8];
#pragma unroll
        for (int i = 0; i < 8; ++i) t[i] = f2bu(w[j * 8 + i]);
        ((uint4*)p)[j] = *(uint4*)t;
    }
}
__device__ inline void store32(float* p, const float* w) {
#pragma unroll
    for (int j = 0; j < 8; ++j) {
        float4 q = {w[j * 4], w[j * 4 + 1], w[j * 4 + 2], w[j * 4 + 3]};
        ((float4*)p)[j] = q;
    }
}

// ---------------- WIDE MFMA GEMM: BM=64, BN=256, 512 threads = 8 waves ----------
// Wave w: rows (w&3)*16, cols (w>>2)*128 -> acc[8] (32 AGPRs/wave).
// C = A[M,K] @ W[N,K]^T + bias; EPI: 0=none, 1=relu, 2=LayerNorm(resid + C).
// EPI=2 requires N==256, gridDim.x==1.
template <int EPI, typename TA, typename TR, typename OT>
__global__ __launch_bounds__(512) void wide_gemm_kernel(
    const TA* __restrict__ A, const bf16* __restrict__ W, const float* __restrict__ bias,
    const TR* __restrict__ resid, const float* __restrict__ gamma, const float* __restrict__ beta,
    OT* __restrict__ C, int M, int N, int K) {
    __shared__ unsigned short smem[16896];  // 33792 B
    unsigned short (*As)[40] = (unsigned short(*)[40])smem;            // 64 x 40
    unsigned short (*Bs)[40] = (unsigned short(*)[40])(smem + 2560);   // 256 x 40
    unsigned short (*Cst)[264] = (unsigned short(*)[264])smem;         // 64 x 264 (overlay)
    const int bm = blockIdx.y * 64, bn = blockIdx.x * 256;
    const int tid = threadIdx.x;
    const int lane = tid & 63, wave = tid >> 6;
    const int l15 = lane & 15, g = lane >> 4;
    const int wrt = (wave & 3) * 16;      // wave's row-tile base
    const int wch = (wave >> 2) * 128;    // wave's col-half base
    const f32x4 zf = {0.f, 0.f, 0.f, 0.f};
    f32x4 acc[8];
#pragma unroll
    for (int ct = 0; ct < 8; ++ct) acc[ct] = zf;

    for (int k0 = 0; k0 < K; k0 += 32) {
        __syncthreads();
        if (tid < 256) {  // A: 64 rows x 32
            const int r = tid >> 2, col = (tid & 3) * 8;
            stage8(&As[r][col], A, (size_t)(bm + r) * K + k0 + col, (bm + r) < M);
        }
#pragma unroll
        for (int pass = 0; pass < 2; ++pass) {  // B: 256 rows x 32
            const int c = tid + pass * 512;
            const int r = c >> 2, col = (c & 3) * 8;
            stage8(&Bs[r][col], W, (size_t)(bn + r) * K + k0 + col, (bn + r) < N);
        }
        __syncthreads();
        const short8 af = *(const short8*)&As[wrt + l15][g * 8];
#pragma unroll
        for (int ct = 0; ct < 8; ++ct) {
            const short8 bf = *(const short8*)&Bs[wch + ct * 16 + l15][g * 8];
            acc[ct] = __builtin_amdgcn_mfma_f32_16x16x32_bf16(af, bf, acc[ct], 0, 0, 0);
        }
    }
    // ---- stage C (bias/relu applied, bf16) ----
    __syncthreads();
#pragma unroll
    for (int ct = 0; ct < 8; ++ct) {
        const int col = wch + ct * 16 + l15;
        const float bv = bias[bn + col];
#pragma unroll
        for (int r = 0; r < 4; ++r) {
            float v = acc[ct][r] + bv;
            if (EPI == 1) v = fmaxf(v, 0.f);
            Cst[wrt + g * 4 + r][col] = f2bu(v);
        }
    }
    __syncthreads();
    // ---- write phase: 8 threads per row, 32 cols each ----
    const int r = tid >> 3, sub = tid & 7;
    const int row = bm + r;
    if (row >= M) return;
    if constexpr (EPI < 2) {
        uint4* dst = (uint4*)((unsigned short*)C + (size_t)row * N + bn + sub * 32);
#pragma unroll
        for (int j = 0; j < 4; ++j) dst[j] = *(const uint4*)&Cst[r][sub * 32 + j * 8];
    } else {
        float v[32];
        load32(v, resid + (size_t)row * 256 + sub * 32);
        float s = 0.f;
#pragma unroll
        for (int j = 0; j < 4; ++j) {
            const uint4 u = *(const uint4*)&Cst[r][sub * 32 + j * 8];
            const unsigned short* us = (const unsigned short*)&u;
#pragma unroll
            for (int i = 0; i < 8; ++i) {
                v[j * 8 + i] += bf2f(us[i]);
                s += v[j * 8 + i];
            }
        }
        s += __shfl_xor(s, 1);
        s += __shfl_xor(s, 2);
        s += __shfl_xor(s, 4);
        const float mean = s * (1.f / 256.f);
        float s2 = 0.f;
#pragma unroll
        for (int i = 0; i < 32; ++i) {
            const float d = v[i] - mean;
            s2 += d * d;
        }
        s2 += __shfl_xor(s2, 1);
        s2 += __shfl_xor(s2, 2);
        s2 += __shfl_xor(s2, 4);
        const float rstd = rsqrtf(s2 * (1.f / 256.f) + 1e-5f);
#pragma unroll
        for (int i = 0; i < 32; ++i) {
            const int c = sub * 32 + i;
            v[i] = (v[i] - mean) * rstd * gamma[c] + beta[c];
        }
        store32(C + (size_t)row * 256 + sub * 32, v);
    }
}

// ---------------- narrow MFMA GEMM (dots only): BM=128, BN=64 ----------------
template <int ACT, typename TA, typename OT>
__global__ __launch_bounds__(256) void gemm_mfma_kernel(const TA* __restrict__ A,
                                                        const bf16* __restrict__ W,
                                                        const float* __restrict__ bias,
                                                        OT* __restrict__ C, int M, int N, int K) {
    __shared__ unsigned short As[128][40];
    __shared__ unsigned short Bs[64][40];
    const int bm = blockIdx.y * 128, bn = blockIdx.x * 64;
    const int tid = threadIdx.x;
    const int lane = tid & 63, wave = tid >> 6;
    const int l15 = lane & 15, g = lane >> 4;
    const f32x4 zf = {0.f, 0.f, 0.f, 0.f};
    f32x4 acc[2][4];
#pragma unroll
    for (int rt = 0; rt < 2; ++rt)
#pragma unroll
        for (int ct = 0; ct < 4; ++ct) acc[rt][ct] = zf;

    for (int k0 = 0; k0 < K; k0 += 32) {
        __syncthreads();
#pragma unroll
        for (int pass = 0; pass < 2; ++pass) {
            const int c = tid + pass * 256;
            const int r = c >> 2, col = (c & 3) * 8;
            stage8(&As[r][col], A, (size_t)(bm + r) * K + k0 + col, (bm + r) < M);
        }
        {
            const int r = tid >> 2, col = (tid & 3) * 8;
            stage8(&Bs[r][col], W, (size_t)(bn + r) * K + k0 + col, (bn + r) < N);
        }
        __syncthreads();
        short8 af[2];
        af[0] = *(const short8*)&As[wave * 32 + l15][g * 8];
        af[1] = *(const short8*)&As[wave * 32 + 16 + l15][g * 8];
#pragma unroll
        for (int ct = 0; ct < 4; ++ct) {
            const short8 bf = *(const short8*)&Bs[ct * 16 + l15][g * 8];
            acc[0][ct] = __builtin_amdgcn_mfma_f32_16x16x32_bf16(af[0], bf, acc[0][ct], 0, 0, 0);
            acc[1][ct] = __builtin_amdgcn_mfma_f32_16x16x32_bf16(af[1], bf, acc[1][ct], 0, 0, 0);
        }
    }
#pragma unroll
    for (int rt = 0; rt < 2; ++rt)
#pragma unroll
        for (int ct = 0; ct < 4; ++ct) {
            const int col = bn + ct * 16 + l15;
            const float bv = bias[col];
#pragma unroll
            for (int r = 0; r < 4; ++r) {
                const int row = bm + wave * 32 + rt * 16 + g * 4 + r;
                if (row < M) {
                    float v = acc[rt][ct][r] + bv;
                    if (ACT == 1) v = fmaxf(v, 0.f);
                    storev(&C[(size_t)row * N + col], v);
                }
            }
        }
}

// ---------------- MFMA flash MHA (round-9 version, no prefetch) ----------------
__global__ __launch_bounds__(256) void mha_mfma_kernel(const bf16* __restrict__ qkv,
                                                       bf16* __restrict__ o) {
    const int qt = blockIdx.x, h = blockIdx.y, b = blockIdx.z;
    const int tid = threadIdx.x;
    const int lane = tid & 63, wave = tid >> 6;
    const int l15 = lane & 15, g = lane >> 4;
    __shared__ unsigned short Kls[KTC][40];
    __shared__ bf16 Vt[HD][136];
    __shared__ bf16 Pls[4][16][136];
    const size_t base = (size_t)b * QQ * 768;
    const int q0 = qt * QT;

    short8 qa = {0, 0, 0, 0, 0, 0, 0, 0};
    {
        const int qg = q0 + wave * 16 + l15;
        if (qg < QQ)
            qa = *(const short8*)(qkv + base + (size_t)qg * 768 + h * HD + g * 8);
    }
    f32x4 accO[2] = {{0.f, 0.f, 0.f, 0.f}, {0.f, 0.f, 0.f, 0.f}};
    float m_run[4], l_run[4];
#pragma unroll
    for (int r = 0; r < 4; ++r) {
        m_run[r] = -1e30f;
        l_run[r] = 0.f;
    }
    const float scale = 0.17677669529663687f;
    const uint4 zero4 = {0u, 0u, 0u, 0u};

    for (int c = 0; c < NCHUNK; ++c) {
        const int k0 = c * KTC;
        __syncthreads();
        {
            const int part = tid & 3, kr = tid >> 2;
#pragma unroll
            for (int pass = 0; pass < 2; ++pass) {
                const int krr = kr + pass * 64;
                const int kg = k0 + krr;
                uint4 kv = (kg < QQ)
                    ? *(const uint4*)(qkv + base + (size_t)kg * 768 + DD + h * HD + part * 8)
                    : zero4;
                *(uint4*)&Kls[krr][part * 8] = kv;
            }
        }
        {
            const int kr = tid >> 1, ch0 = (tid & 1) * 16;
            const int kg = k0 + kr;
            uint4 v0 = zero4, v1 = zero4;
            if (kg < QQ) {
                const bf16* pv = qkv + base + (size_t)kg * 768 + 2 * DD + h * HD + ch0;
                v0 = *(const uint4*)pv;
                v1 = *(const uint4*)(pv + 8);
            }
            const unsigned short* u0 = (const unsigned short*)&v0;
            const unsigned short* u1 = (const unsigned short*)&v1;
#pragma unroll
            for (int j = 0; j < 8; ++j) {
                ((unsigned short*)&Vt[ch0 + j][kr])[0] = u0[j];
                ((unsigned short*)&Vt[ch0 + 8 + j][kr])[0] = u1[j];
            }
        }
        __syncthreads();

        f32x4 s[8];
#pragma unroll
        for (int t = 0; t < 8; ++t) {
            const short8 kb = *(const short8*)&Kls[t * 16 + l15][g * 8];
            const f32x4 z = {0.f, 0.f, 0.f, 0.f};
            s[t] = __builtin_amdgcn_mfma_f32_16x16x32_bf16(qa, kb, z, 0, 0, 0);
        }
        float mx[4] = {-1e30f, -1e30f, -1e30f, -1e30f};
#pragma unroll
        for (int t = 0; t < 8; ++t) {
            const bool cv = (k0 + t * 16 + l15) < QQ;
#pragma unroll
            for (int r = 0; r < 4; ++r) {
                const float v = cv ? s[t][r] * scale : -1e30f;
                s[t][r] = v;
                mx[r] = fmaxf(mx[r], v);
            }
        }
#pragma unroll
        for (int r = 0; r < 4; ++r) {
            mx[r] = fmaxf(mx[r], __shfl_xor(mx[r], 1));
            mx[r] = fmaxf(mx[r], __shfl_xor(mx[r], 2));
            mx[r] = fmaxf(mx[r], __shfl_xor(mx[r], 4));
            mx[r] = fmaxf(mx[r], __shfl_xor(mx[r], 8));
        }
        float alpha[4], rs[4];
#pragma unroll
        for (int r = 0; r < 4; ++r) {
            const float mn = fmaxf(m_run[r], mx[r]);
            alpha[r] = __expf(m_run[r] - mn);
            m_run[r] = mn;
            rs[r] = 0.f;
        }
#pragma unroll
        for (int t = 0; t < 8; ++t) {
#pragma unroll
            for (int r = 0; r < 4; ++r) {
                const float p = __expf(s[t][r] - m_run[r]);
                rs[r] += p;
                Pls[wave][g * 4 + r][t * 16 + l15] = __float2bfloat16(p);
            }
        }
#pragma unroll
        for (int r = 0; r < 4; ++r) {
            rs[r] += __shfl_xor(rs[r], 1);
            rs[r] += __shfl_xor(rs[r], 2);
            rs[r] += __shfl_xor(rs[r], 4);
            rs[r] += __shfl_xor(rs[r], 8);
            l_run[r] = l_run[r] * alpha[r] + rs[r];
        }
#pragma unroll
        for (int t2 = 0; t2 < 2; ++t2)
#pragma unroll
            for (int r = 0; r < 4; ++r) accO[t2][r] *= alpha[r];
#pragma unroll
        for (int s4 = 0; s4 < 4; ++s4) {
            const short8 pa = *(const short8*)&Pls[wave][l15][s4 * 32 + g * 8];
#pragma unroll
            for (int t2 = 0; t2 < 2; ++t2) {
                const short8 vb = *(const short8*)&Vt[t2 * 16 + l15][s4 * 32 + g * 8];
                accO[t2] = __builtin_amdgcn_mfma_f32_16x16x32_bf16(pa, vb, accO[t2], 0, 0, 0);
            }
        }
    }
#pragma unroll
    for (int r = 0; r < 4; ++r) {
        const int row = q0 + wave * 16 + g * 4 + r;
        if (row < QQ) {
            const float inv = 1.f / l_run[r];
#pragma unroll
            for (int t2 = 0; t2 < 2; ++t2) {
                storev(&o[((size_t)b * QQ + row) * DD + h * HD + t2 * 16 + l15],
                       accO[t2][r] * inv);
            }
        }
    }
}

// ---------------- deformable gather from precomputed val ----------------
__global__ __launch_bounds__(256) void deform_gather_kernel(const float* __restrict__ dots,
                                                            const bf16* __restrict__ val,
                                                            bf16* __restrict__ samp) {
    const int b = blockIdx.y;
    const int q0 = blockIdx.x * GQB;
    const int tid = threadIdx.x;
    const int q = tid >> 5, hp = tid & 31, h = hp >> 2;
    const int qg = q0 + q;
    __shared__ float Gs[GQB][32][36];
    float accv[32];
#pragma unroll
    for (int j = 0; j < 32; ++j) accv[j] = 0.f;

    if (qg < QQ) {
        const float* dr = dots + ((size_t)b * QQ + qg) * 128;
        const float ox = dr[hp * 2], oy = dr[hp * 2 + 1];
        const float ad = dr[64 + hp];
        const float rx = dr[96], ry = dr[97];
        float mx = ad;
        mx = fmaxf(mx, __shfl_xor(mx, 1));
        mx = fmaxf(mx, __shfl_xor(mx, 2));
        const float e = __expf(ad - mx);
        float sm = e;
        sm += __shfl_xor(sm, 1);
        sm += __shfl_xor(sm, 2);
        const float a = e / sm;
        const float refx = 1.f / (1.f + __expf(-rx));
        const float refy = 1.f / (1.f + __expf(-ry));
        const float x = (refx + ox * (1.f / WW2)) * WW2 - 0.5f;
        const float y = (refy + oy * (1.f / HH)) * HH - 0.5f;
        const float x0f = floorf(x), y0f = floorf(y);
        const float lx = x - x0f, ly = y - y0f;
        const int x0 = (int)x0f, y0 = (int)y0f;
        const float cw[4] = {(1 - lx) * (1 - ly), lx * (1 - ly), (1 - lx) * ly, lx * ly};
        const int cx[4] = {x0, x0 + 1, x0, x0 + 1};
        const int cy[4] = {y0, y0, y0 + 1, y0 + 1};
        const bf16* vb = val + (size_t)b * HWTOT * DD + h * HD;
#pragma unroll
        for (int cc = 0; cc < 4; ++cc) {
            const bool valid = cx[cc] >= 0 && cx[cc] < WW2 && cy[cc] >= 0 && cy[cc] < HH;
            const float w = valid ? a * cw[cc] : 0.f;
            const int xi = min(max(cx[cc], 0), WW2 - 1);
            const int yi = min(max(cy[cc], 0), HH - 1);
            const bf16* p = vb + (size_t)(yi * WW2 + xi) * DD;
            const uint4 u0 = *(const uint4*)p;
            const uint4 u1 = *(const uint4*)(p + 8);
            const uint4 u2 = *(const uint4*)(p + 16);
            const uint4 u3 = *(const uint4*)(p + 24);
            const unsigned short* s0 = (const unsigned short*)&u0;
            const unsigned short* s1 = (const unsigned short*)&u1;
            const unsigned short* s2 = (const unsigned short*)&u2;
            const unsigned short* s3 = (const unsigned short*)&u3;
#pragma unroll
            for (int j = 0; j < 8; ++j) {
                accv[j] += w * bf2f(s0[j]);
                accv[8 + j] += w * bf2f(s1[j]);
                accv[16 + j] += w * bf2f(s2[j]);
                accv[24 + j] += w * bf2f(s3[j]);
            }
        }
    }
#pragma unroll
    for (int j4 = 0; j4 < 8; ++j4) {
        float4 t = {accv[j4 * 4], accv[j4 * 4 + 1], accv[j4 * 4 + 2], accv[j4 * 4 + 3]};
        *(float4*)&Gs[q][hp][j4 * 4] = t;
    }
    __syncthreads();
    {
        const int q2 = tid >> 5, idx5 = tid & 31;
        const int h2 = idx5 >> 2, cg = idx5 & 3;
        if (q0 + q2 < QQ) {
            float s[8] = {0.f, 0.f, 0.f, 0.f, 0.f, 0.f, 0.f, 0.f};
#pragma unroll
            for (int p = 0; p < 4; ++p) {
                const float4 a0 = *(const float4*)&Gs[q2][h2 * 4 + p][cg * 8];
                const float4 a1 = *(const float4*)&Gs[q2][h2 * 4 + p][cg * 8 + 4];
                s[0] += a0.x; s[1] += a0.y; s[2] += a0.z; s[3] += a0.w;
                s[4] += a1.x; s[5] += a1.y; s[6] += a1.z; s[7] += a1.w;
            }
            unsigned short outp[8];
#pragma unroll
            for (int j = 0; j < 8; ++j) outp[j] = f2bu(s[j]);
            bf16* op = samp + ((size_t)b * QQ + q0 + q2) * DD + h2 * HD + cg * 8;
            *(uint4*)op = *(uint4*)outp;
        }
    }
}

extern "C" void kernel_launch(void* const* d_in, const int* in_sizes, int n_in,
                              void* d_out, int out_size, void* d_ws, size_t ws_size,
                              hipStream_t stream) {
    const float* tgt = (const float*)d_in[0];
    const float* memory = (const float*)d_in[1];
    const float* in_proj_w = (const float*)d_in[4];
    const float* in_proj_b = (const float*)d_in[5];
    const float* out_proj_w = (const float*)d_in[6];
    const float* out_proj_b = (const float*)d_in[7];
    const float* norm1_s = (const float*)d_in[8];
    const float* norm1_b = (const float*)d_in[9];
    const float* norm2_s = (const float*)d_in[10];
    const float* norm2_b = (const float*)d_in[11];
    const float* norm3_s = (const float*)d_in[12];
    const float* norm3_b = (const float*)d_in[13];
    const float* vproj_w = (const float*)d_in[14];
    const float* vproj_b = (const float*)d_in[15];
    const float* offs_w = (const float*)d_in[16];
    const float* offs_b = (const float*)d_in[17];
    const float* attw_w = (const float*)d_in[18];
    const float* attw_b = (const float*)d_in[19];
    const float* ref_w = (const float*)d_in[20];
    const float* ref_b = (const float*)d_in[21];
    const float* cout_w = (const float*)d_in[22];
    const float* cout_b = (const float*)d_in[23];
    const float* ffn_w1 = (const float*)d_in[24];
    const float* ffn_b1 = (const float*)d_in[25];
    const float* ffn_w2 = (const float*)d_in[26];
    const float* ffn_b2 = (const float*)d_in[27];

    const int M = BB * QQ;  // 7200
    bf16* ws = (bf16*)d_ws;
    size_t off = 0;
    bf16* qkv = ws + off;  off += (size_t)M * 768;
    bf16* o = ws + off;    off += (size_t)M * DD;
    bf16* t1 = ws + off;   off += (size_t)M * DD;
    bf16* ffh = ws + off;  off += (size_t)M * FFD;
    bf16* wpk = ws + off;  off += 950272;
    float* dbias = (float*)(ws + off); off += 256;
    bf16* val = ws + off;  off += (size_t)BB * HWTOT * DD;
    bf16* samp = o;                     // alias: o dead after out_proj
    bf16* t2n = qkv;                    // alias: qkv dead after mha
    float* dots = (float*)ffh;          // alias: ffh written only after gather

    bf16* w_in = wpk;
    bf16* w_out = wpk + 196608;
    bf16* w_cout = wpk + 262144;
    bf16* w_ffn1 = wpk + 327680;
    bf16* w_ffn2 = wpk + 589824;
    bf16* w_vproj = wpk + 851968;
    bf16* w_dots = wpk + 917504;

    const int MT64 = (M + 63) / 64;  // 113

    // 0. pack weights to bf16
    pack_kernel<<<(950272 + 128 + 255) / 256, 256, 0, stream>>>(
        in_proj_w, out_proj_w, cout_w, ffn_w1, ffn_w2, vproj_w, offs_w, attw_w, ref_w,
        offs_b, attw_b, ref_b, wpk, dbias);
    // 1. value projection (wide, A read once, 512-thread occupancy)
    wide_gemm_kernel<0, float, float, bf16><<<dim3(1, BB * HWTOT / 64), 512, 0, stream>>>(
        memory, w_vproj, vproj_b, nullptr, nullptr, nullptr, val, BB * HWTOT, DD, DD);
    // 2. QKV projection
    wide_gemm_kernel<0, float, float, bf16><<<dim3(3, MT64), 512, 0, stream>>>(
        tgt, w_in, in_proj_b, nullptr, nullptr, nullptr, qkv, M, 768, DD);
    // 3. self-attention
    mha_mfma_kernel<<<dim3((QQ + QT - 1) / QT, NH, BB), 256, 0, stream>>>(qkv, o);
    // 4. out projection + LN1 fused (resid = tgt fp32) -> t1 bf16
    wide_gemm_kernel<2, bf16, float, bf16><<<dim3(1, MT64), 512, 0, stream>>>(
        o, w_out, out_proj_b, tgt, norm1_s, norm1_b, t1, M, DD, DD);
    // 5. deform param dots GEMM -> fp32 [M,128]
    gemm_mfma_kernel<0, bf16, float><<<dim3(2, (M + 127) / 128), 256, 0, stream>>>(
        t1, w_dots, dbias, dots, M, 128, DD);
    // 6. gather from val
    deform_gather_kernel<<<dim3((QQ + GQB - 1) / GQB, BB), 256, 0, stream>>>(dots, val, samp);
    // 7. cross-attn out projection + LN2 fused (resid = t1) -> t2n bf16
    wide_gemm_kernel<2, bf16, bf16, bf16><<<dim3(1, MT64), 512, 0, stream>>>(
        samp, w_cout, cout_b, t1, norm2_s, norm2_b, t2n, M, DD, DD);
    // 8. FFN layer 1 (+ReLU)
    wide_gemm_kernel<1, bf16, float, bf16><<<dim3(4, MT64), 512, 0, stream>>>(
        t2n, w_ffn1, ffn_b1, nullptr, nullptr, nullptr, ffh, M, FFD, DD);
    // 9. FFN layer 2 + LN3 fused (resid = t2n) -> fp32 d_out
    wide_gemm_kernel<2, bf16, bf16, float><<<dim3(1, MT64), 512, 0, stream>>>(
        ffh, w_ffn2, ffn_b2, t2n, norm3_s, norm3_b, (float*)d_out, M, DD, FFD);
}